// Round 17
// baseline (9254.539 us; speedup 1.0000x reference)
//
#include <hip/hip_runtime.h>
#include <stdint.h>

#define TT 512
#define BB 64
#define II 256
#define HS 512          // H
#define HHALF 256       // HH
#define R4H 2048        // 4*H
#define HB_STRIDE 16384 // 64 batches * 256 unit-pair words per h buffer

typedef __attribute__((ext_vector_type(8))) short short8v;  // 8 bf16 = 4 VGPR
typedef __attribute__((ext_vector_type(4))) float f32x4;

// ---------------------------------------------------------------------------
// Phase 1: PG[t][r][b] = (b_ih[r]+b_hh[r]) + sum_k W_ih[r][k] * X[b][t][k]
// ---------------------------------------------------------------------------
__global__ __launch_bounds__(256) void pregemm(
    const float* __restrict__ X,    // [B][T][I]
    const float* __restrict__ Wih,  // [4H][I]
    const float* __restrict__ bih,
    const float* __restrict__ bhh,
    float* __restrict__ PG)         // [T][4H][B]
{
  __shared__ __align__(16) float Xs[64][68];
  __shared__ __align__(16) float Ws[64][68];
  const int t = blockIdx.x;
  const int rbase = blockIdx.y * 64;
  const int tid = threadIdx.x;
  const int cg = tid & 15;
  const int rg = tid >> 4;

  float acc[4][4] = {};

  for (int k0 = 0; k0 < II; k0 += 64) {
    {
      int b = tid >> 2, kq = tid & 3;
      const float* src = X + ((size_t)b * TT + t) * II + k0 + kq * 16;
      #pragma unroll
      for (int i = 0; i < 16; i += 4) {
        float4 v = *(const float4*)(src + i);
        int kk = kq * 16 + i;
        Xs[kk + 0][b] = v.x; Xs[kk + 1][b] = v.y;
        Xs[kk + 2][b] = v.z; Xs[kk + 3][b] = v.w;
      }
    }
    {
      int r = tid >> 2, kq = tid & 3;
      const float* src = Wih + (size_t)(rbase + r) * II + k0 + kq * 16;
      #pragma unroll
      for (int i = 0; i < 16; i += 4) {
        float4 v = *(const float4*)(src + i);
        int kk = kq * 16 + i;
        Ws[kk + 0][r] = v.x; Ws[kk + 1][r] = v.y;
        Ws[kk + 2][r] = v.z; Ws[kk + 3][r] = v.w;
      }
    }
    __syncthreads();
    #pragma unroll 8
    for (int kk = 0; kk < 64; ++kk) {
      float4 a = *(const float4*)&Ws[kk][rg * 4];
      float4 x = *(const float4*)&Xs[kk][cg * 4];
      float av[4] = {a.x, a.y, a.z, a.w};
      float xv[4] = {x.x, x.y, x.z, x.w};
      #pragma unroll
      for (int i = 0; i < 4; ++i)
        #pragma unroll
        for (int j = 0; j < 4; ++j)
          acc[i][j] = fmaf(av[i], xv[j], acc[i][j]);
    }
    __syncthreads();
  }

  #pragma unroll
  for (int i = 0; i < 4; ++i) {
    int row = rbase + rg * 4 + i;
    float bias = bih[row] + bhh[row];
    float4 o;
    o.x = acc[i][0] + bias; o.y = acc[i][1] + bias;
    o.z = acc[i][2] + bias; o.w = acc[i][3] + bias;
    *(float4*)&PG[((size_t)t * R4H + row) * BB + cg * 4] = o;
  }
}

// ---------------------------------------------------------------------------
__device__ __forceinline__ uint32_t bf16r(float f) {
  uint32_t u = __float_as_uint(f);
  u += 0x7fffu + ((u >> 16) & 1u);
  return u >> 16;
}

// init: hbT[0][b][uh] = pack(bf16(h[2uh]), bf16(h[2uh+1]))  (layout [64][256])
__global__ void init_h(const float* __restrict__ mem, uint32_t* __restrict__ hb)
{
  int idx = blockIdx.x * 256 + threadIdx.x;
  if (idx < HB_STRIDE) {
    int b = idx >> 8, uh = idx & 255;
    float lo = mem[(size_t)b * 1280 + 256 + 2 * uh];
    float hi = mem[(size_t)b * 1280 + 256 + 2 * uh + 1];
    hb[idx] = bf16r(lo) | (bf16r(hi) << 16);
  }
}

// ---------------------------------------------------------------------------
// Cross-XCD h hand-off (proven R6): relaxed agent-scope EXCHANGE stores (RMW
// performed at the IF coherence point; vmcnt(0) ack => globally visible) +
// relaxed agent-scope loads (bypass stale L1/L2). No wbl2/inv sweeps.
// ---------------------------------------------------------------------------
__device__ __forceinline__ void store_coh_u32(uint32_t* p, uint32_t v) {
  (void)__hip_atomic_exchange(p, v, __ATOMIC_RELAXED, __HIP_MEMORY_SCOPE_AGENT);
}
__device__ __forceinline__ uint32_t load_coh_u32(const uint32_t* p) {
  return __hip_atomic_load(p, __ATOMIC_RELAXED, __HIP_MEMORY_SCOPE_AGENT);
}

// gsum addressing: 2-way-max bank pattern via XOR of bit4 with (row>>2)&1
#define GIDX(row, col) (((row) << 6) + ((col) ^ ((((row) >> 2) & 1) << 4)))

// ---------------------------------------------------------------------------
// Persistent LSTM, MFMA + LDS-A-fragments (R17). grid = 64 WGs x 512 thr.
// WG g owns units [g*8, g*8+8) = 32 gate rows, ALL 64 batches. Per step:
//   gates[32 rows][64 b] = sum_k W_bf16 x h_bf16 via mfma_f32_16x16x32_bf16.
// Wave wu = ONE C-tile: row-tile rt = wu>>2, batch-tile bt = wu&3.
//
// R12-R16 lesson: the backend pins this kernel's arch-VGPR budget at ~128
// and spills any large per-lane W array to scratch (R16: VGPR=76 with the
// 64-reg aF[] in scratch; WRITE_SIZE 329 MB; 17 us/step). R17 removes the
// register array entirely: W slice staged ONCE into LDS pre-packed in MFMA
// A-fragment order; inner loop reads it with ds_read_b128 at
// base + lane*16 (canonical conflict-free pattern, LDS pipe overlaps VMEM
// and MFMA). Per-lane live set ~60 VGPRs -> nothing to spill.
//
// WA layout: slot(rt,ks,ln) = rt*1024 + ks*64 + ln; 4 u32 per slot; lane ln
// holds A[row=rt*16+(ln&15)][k=(ln>>4)*8 + ks*32 + j] as 4 bf16-pair words.
// h stored TRANSPOSED hbT[b][u/2]; B-frag = 4 consecutive u32 per lane
// (layout end-to-end verified: R12-R16 passed, absmax 0.0078).
// Elementwise: tid<256, thread = (unit-pair p = tid>>6, batch = lane).
// Sync: single 64-arrival monotonic counter, relaxed agent RMWs (proven).
// ---------------------------------------------------------------------------
__global__ __launch_bounds__(512) void lstm_persistent(
    const float* __restrict__ mem,   // [B][1280]
    const float* __restrict__ Whh,   // [4H][H] f32
    float* __restrict__ PG,          // [T][4H][B]
    uint32_t* __restrict__ hb,       // [2][64][256] packed bf16x2, transposed
    float* __restrict__ outmem,      // [B][1280]
    unsigned* __restrict__ bar)      // cnt@0, gen@64
{
  __shared__ __align__(16) uint32_t WA[2 * 16 * 64 * 4];  // 32 KB
  __shared__ float gsum[32 * 64];                          // 8 KB

  const int g    = blockIdx.x;       // 0..63
  const int tid  = threadIdx.x;
  const int wu   = tid >> 6;         // wave 0..7
  const int lane = tid & 63;
  const int l15  = lane & 15;
  const int lq   = lane >> 4;        // 0..3
  const int bt   = wu & 3;           // batch tile 0..3
  const int rt   = wu >> 2;          // row tile 0..1
  const int u0   = g * 8;

  unsigned* cnt = bar;
  unsigned* gen = bar + 64;

  // ---- stage W slice into LDS in A-fragment order (once) ----
  #pragma unroll
  for (int s = 0; s < 4; ++s) {
    int slot = s * 512 + tid;          // 0..2047
    int srt  = slot >> 10;             // 0..1
    int rem  = slot & 1023;
    int sks  = rem >> 6;               // 0..15
    int ln   = rem & 63;
    int sl15 = ln & 15, slq = ln >> 4;
    int lr   = srt * 16 + sl15;        // local gate row
    int grow = (lr >> 3) * HS + u0 + (lr & 7);
    const float* wp = Whh + (size_t)grow * HS + slq * 8 + sks * 32;
    float4 x0 = *(const float4*)(wp);
    float4 x1 = *(const float4*)(wp + 4);
    uint32_t* dst = WA + (size_t)slot * 4;
    dst[0] = bf16r(x0.x) | (bf16r(x0.y) << 16);
    dst[1] = bf16r(x0.z) | (bf16r(x0.w) << 16);
    dst[2] = bf16r(x1.x) | (bf16r(x1.y) << 16);
    dst[3] = bf16r(x1.z) | (bf16r(x1.w) << 16);
  }

  // ---- elementwise state: tid<256, thread = (pair p = tid>>6, batch eb) ----
  const int p = tid >> 6;            // unit-pair 0..3 (valid for tid<256)
  const int eb = lane;
  float c0 = 0.f, c1 = 0.f, m0 = 0.f, m1 = 0.f, h0l = 0.f, h1l = 0.f;
  if (tid < 256) {
    c0 = mem[(size_t)eb * 1280 + 768 + u0 + 2 * p];
    c1 = mem[(size_t)eb * 1280 + 768 + u0 + 2 * p + 1];
    if (u0 < HHALF) {
      m0 = mem[(size_t)eb * 1280 + u0 + 2 * p];
      m1 = mem[(size_t)eb * 1280 + u0 + 2 * p + 1];
    }
  }

  // ---- pg prefetch for t=0 (1 tile x 4 regs per lane) ----
  float pg[4];
  #pragma unroll
  for (int r = 0; r < 4; ++r) {
    int lr = rt * 16 + lq * 4 + r;
    pg[r] = PG[((size_t)0 * R4H + (lr >> 3) * HS + u0 + (lr & 7)) * BB + bt * 16 + l15];
  }

  __syncthreads();  // W staged

  const uint32_t* waBase = WA + ((size_t)(rt * 16) * 64 + lane) * 4;

  for (int t = 0; t < TT; ++t) {
    // ---- A via LDS b128, B via coherent loads, MFMA over K=512 ----
    f32x4 acc = {0.f, 0.f, 0.f, 0.f};
    const uint32_t* hT = hb + (size_t)(t & 1) * HB_STRIDE
                            + (size_t)(bt * 16 + l15) * 256 + lq * 4;
    #pragma unroll
    for (int ks = 0; ks < 16; ++ks) {
      short8v av = *(const short8v*)(waBase + ks * 256);  // ds_read_b128
      union { uint32_t u[4]; short8v v; } bf;
      #pragma unroll
      for (int m = 0; m < 4; ++m) bf.u[m] = load_coh_u32(hT + ks * 16 + m);
      acc = __builtin_amdgcn_mfma_f32_16x16x32_bf16(av, bf.v, acc, 0, 0, 0);
    }

    // ---- add pre-gates, write to gsum (2-way-max banks) ----
    {
      const int colw = bt * 16 + l15;
      #pragma unroll
      for (int r = 0; r < 4; ++r) {
        int row = rt * 16 + lq * 4 + r;
        gsum[GIDX(row, colw)] = acc[r] + pg[r];
      }
    }
    __syncthreads();

    // ---- elementwise: 2 cells (units u0+2p, u0+2p+1) x batch eb ----
    if (tid < 256) {
      const int ul0 = 2 * p, ul1 = 2 * p + 1;
      float gi0 = gsum[GIDX( 0 + ul0, eb)];
      float gf0 = gsum[GIDX( 8 + ul0, eb)];
      float gg0 = gsum[GIDX(16 + ul0, eb)];
      float go0 = gsum[GIDX(24 + ul0, eb)];
      float gi1 = gsum[GIDX( 0 + ul1, eb)];
      float gf1 = gsum[GIDX( 8 + ul1, eb)];
      float gg1 = gsum[GIDX(16 + ul1, eb)];
      float go1 = gsum[GIDX(24 + ul1, eb)];
      float si0 = 1.f / (1.f + __expf(-gi0));
      float sf0 = 1.f / (1.f + __expf(-gf0));
      float so0 = 1.f / (1.f + __expf(-go0));
      float si1 = 1.f / (1.f + __expf(-gi1));
      float sf1 = 1.f / (1.f + __expf(-gf1));
      float so1 = 1.f / (1.f + __expf(-go1));
      c0 = sf0 * c0 + si0 * tanhf(gg0);
      c1 = sf1 * c1 + si1 * tanhf(gg1);
      float h0 = so0 * tanhf(c0);
      float h1 = so1 * tanhf(c1);
      h0l = h0; h1l = h1;
      // transposed packed store: hbT[eb][g*4+p] (unit pair is thread-local)
      store_coh_u32(&hb[(size_t)((t + 1) & 1) * HB_STRIDE + (size_t)eb * 256 + g * 4 + p],
                    bf16r(h0) | (bf16r(h1) << 16));
      float out0 = h0, out1 = h1;
      if (u0 < HHALF) { m0 = fmaxf(m0, h0); m1 = fmaxf(m1, h1); out0 = m0; out1 = m1; }
      PG[((size_t)t * R4H + u0 + 2 * p) * BB + eb]     = out0;  // stash
      PG[((size_t)t * R4H + u0 + 2 * p + 1) * BB + eb] = out1;
    }

    // ---- barrier: release = vmcnt(0) on the exchange h-stores ----
    asm volatile("s_waitcnt vmcnt(0)" ::: "memory");
    __syncthreads();
    // pg prefetch for t+1 hides under the barrier
    if (t + 1 < TT) {
      #pragma unroll
      for (int r = 0; r < 4; ++r) {
        int lr = rt * 16 + lq * 4 + r;
        pg[r] = PG[((size_t)(t + 1) * R4H + (lr >> 3) * HS + u0 + (lr & 7)) * BB + bt * 16 + l15];
      }
    }
    if (tid == 0) {
      unsigned a = __hip_atomic_fetch_add(cnt, 1u, __ATOMIC_RELAXED,
                                          __HIP_MEMORY_SCOPE_AGENT);
      if (a == 64u * (unsigned)(t + 1) - 1u)
        (void)__hip_atomic_exchange(gen, (unsigned)(t + 1), __ATOMIC_RELAXED,
                                    __HIP_MEMORY_SCOPE_AGENT);
      // failsafe cap: fast wrong-answer instead of a hang; expected wait ~us.
      int spins = 0;
      while (__hip_atomic_load(gen, __ATOMIC_RELAXED,
                               __HIP_MEMORY_SCOPE_AGENT) < (unsigned)(t + 1)) {
        __builtin_amdgcn_s_sleep(1);
        if (++spins > (1 << 16)) break;
      }
    }
    __syncthreads();
  }

  // ---- finals ----
  if (tid < 256) {
    outmem[(size_t)eb * 1280 + 256 + u0 + 2 * p]     = h0l;
    outmem[(size_t)eb * 1280 + 256 + u0 + 2 * p + 1] = h1l;
    outmem[(size_t)eb * 1280 + 768 + u0 + 2 * p]     = c0;
    outmem[(size_t)eb * 1280 + 768 + u0 + 2 * p + 1] = c1;
    if (u0 < HHALF) {
      outmem[(size_t)eb * 1280 + u0 + 2 * p]     = m0;
      outmem[(size_t)eb * 1280 + u0 + 2 * p + 1] = m1;
    }
  }
}

// ---------------------------------------------------------------------------
// Phase 3: out[b][t][u] = PG[t][u][b]  (u < 512)
// ---------------------------------------------------------------------------
__global__ __launch_bounds__(256) void transpose_out(
    const float* __restrict__ PG, float* __restrict__ out)
{
  __shared__ __align__(16) float tileS[64][68];
  const int t = blockIdx.x;
  const int u0 = blockIdx.y * 64;
  const int tid = threadIdx.x;

  {
    int cg = tid & 15, rg = tid >> 4;
    const float* src = PG + (size_t)t * R4H * BB + (size_t)u0 * BB;
    #pragma unroll
    for (int i = 0; i < 4; ++i) {
      int u = rg * 4 + i;
      float4 v = *(const float4*)(src + (size_t)u * BB + cg * 4);
      *(float4*)&tileS[u][cg * 4] = v;
    }
  }
  __syncthreads();
  {
    int ug = tid & 15, bg = tid >> 4;
    #pragma unroll
    for (int i = 0; i < 4; ++i) {
      int b = bg * 4 + i;
      float4 o;
      o.x = tileS[ug * 4 + 0][b];
      o.y = tileS[ug * 4 + 1][b];
      o.z = tileS[ug * 4 + 2][b];
      o.w = tileS[ug * 4 + 3][b];
      *(float4*)&out[((size_t)b * TT + t) * HS + u0 + ug * 4] = o;
    }
  }
}

// ---------------------------------------------------------------------------
extern "C" void kernel_launch(void* const* d_in, const int* in_sizes, int n_in,
                              void* d_out, int out_size, void* d_ws, size_t ws_size,
                              hipStream_t stream)
{
  const float* X   = (const float*)d_in[0];
  const float* mem = (const float*)d_in[1];
  const float* Wih = (const float*)d_in[2];
  const float* Whh = (const float*)d_in[3];
  const float* bih = (const float*)d_in[4];
  const float* bhh = (const float*)d_in[5];

  float* out = (float*)d_out;
  float* outmem = out + (size_t)BB * TT * HS;

  float* PG     = (float*)d_ws;                      // 512*2048*64 f32 = 256 MB
  uint32_t* hbp = (uint32_t*)(PG + (size_t)TT * R4H * BB);  // 2*16384 u32
  unsigned* bar = (unsigned*)(hbp + 2 * HB_STRIDE);  // 2048 u32

  hipMemsetAsync(bar, 0, 2048 * sizeof(unsigned), stream);
  init_h<<<dim3(HB_STRIDE / 256), dim3(256), 0, stream>>>(mem, hbp);
  pregemm<<<dim3(TT, 32), dim3(256), 0, stream>>>(X, Wih, bih, bhh, PG);
  lstm_persistent<<<dim3(64), dim3(512), 0, stream>>>(mem, Whh, PG, hbp, outmem, bar);
  transpose_out<<<dim3(TT, 8), dim3(256), 0, stream>>>(PG, out);
}

// Round 18
// 3022.799 us; speedup vs baseline: 3.0616x; 3.0616x over previous
//
#include <hip/hip_runtime.h>
#include <stdint.h>

#define TT 512
#define BB 64
#define II 256
#define HS 512          // H
#define HHALF 256       // HH
#define R4H 2048        // 4*H
#define HB_STRIDE 16384 // 256 unit-pair rows x 64 batches per h buffer

typedef __attribute__((ext_vector_type(8))) short short8v;  // 8 bf16 = 4 VGPR
typedef __attribute__((ext_vector_type(4))) float f32x4;

// ---------------------------------------------------------------------------
// Phase 1: PG[t][r][b] = (b_ih[r]+b_hh[r]) + sum_k W_ih[r][k] * X[b][t][k]
// ---------------------------------------------------------------------------
__global__ __launch_bounds__(256) void pregemm(
    const float* __restrict__ X,    // [B][T][I]
    const float* __restrict__ Wih,  // [4H][I]
    const float* __restrict__ bih,
    const float* __restrict__ bhh,
    float* __restrict__ PG)         // [T][4H][B]
{
  __shared__ __align__(16) float Xs[64][68];
  __shared__ __align__(16) float Ws[64][68];
  const int t = blockIdx.x;
  const int rbase = blockIdx.y * 64;
  const int tid = threadIdx.x;
  const int cg = tid & 15;
  const int rg = tid >> 4;

  float acc[4][4] = {};

  for (int k0 = 0; k0 < II; k0 += 64) {
    {
      int b = tid >> 2, kq = tid & 3;
      const float* src = X + ((size_t)b * TT + t) * II + k0 + kq * 16;
      #pragma unroll
      for (int i = 0; i < 16; i += 4) {
        float4 v = *(const float4*)(src + i);
        int kk = kq * 16 + i;
        Xs[kk + 0][b] = v.x; Xs[kk + 1][b] = v.y;
        Xs[kk + 2][b] = v.z; Xs[kk + 3][b] = v.w;
      }
    }
    {
      int r = tid >> 2, kq = tid & 3;
      const float* src = Wih + (size_t)(rbase + r) * II + k0 + kq * 16;
      #pragma unroll
      for (int i = 0; i < 16; i += 4) {
        float4 v = *(const float4*)(src + i);
        int kk = kq * 16 + i;
        Ws[kk + 0][r] = v.x; Ws[kk + 1][r] = v.y;
        Ws[kk + 2][r] = v.z; Ws[kk + 3][r] = v.w;
      }
    }
    __syncthreads();
    #pragma unroll 8
    for (int kk = 0; kk < 64; ++kk) {
      float4 a = *(const float4*)&Ws[kk][rg * 4];
      float4 x = *(const float4*)&Xs[kk][cg * 4];
      float av[4] = {a.x, a.y, a.z, a.w};
      float xv[4] = {x.x, x.y, x.z, x.w};
      #pragma unroll
      for (int i = 0; i < 4; ++i)
        #pragma unroll
        for (int j = 0; j < 4; ++j)
          acc[i][j] = fmaf(av[i], xv[j], acc[i][j]);
    }
    __syncthreads();
  }

  #pragma unroll
  for (int i = 0; i < 4; ++i) {
    int row = rbase + rg * 4 + i;
    float bias = bih[row] + bhh[row];
    float4 o;
    o.x = acc[i][0] + bias; o.y = acc[i][1] + bias;
    o.z = acc[i][2] + bias; o.w = acc[i][3] + bias;
    *(float4*)&PG[((size_t)t * R4H + row) * BB + cg * 4] = o;
  }
}

// ---------------------------------------------------------------------------
__device__ __forceinline__ uint32_t bf16r(float f) {
  uint32_t u = __float_as_uint(f);
  u += 0x7fffu + ((u >> 16) & 1u);
  return u >> 16;
}

// init (unit-major, R9-proven coalesced layout):
// hb[0][uh*64 + b] = pack(bf16(h[2uh]), bf16(h[2uh+1]))
__global__ void init_h(const float* __restrict__ mem, uint32_t* __restrict__ hb)
{
  int idx = blockIdx.x * 256 + threadIdx.x;
  if (idx < HB_STRIDE) {
    int uh = idx >> 6, b = idx & 63;
    float lo = mem[(size_t)b * 1280 + 256 + 2 * uh];
    float hi = mem[(size_t)b * 1280 + 256 + 2 * uh + 1];
    hb[idx] = bf16r(lo) | (bf16r(hi) << 16);
  }
}

// ---------------------------------------------------------------------------
// Cross-XCD h hand-off (proven R6): relaxed agent-scope EXCHANGE stores (RMW
// performed at the IF coherence point; vmcnt(0) ack => globally visible) +
// relaxed agent-scope loads (bypass stale L1/L2). No wbl2/inv sweeps.
// R12-R17 lesson: these MUST be coalesced. Scattered 4B sc1 traffic is
// request-rate bound at the IF (32768 load req/WG/step + 16384 partial-line
// write-throughs/step = 17 us steps, WRITE_SIZE +226 MB) regardless of
// where W lives (VGPR/scratch/LDS all identical). Unit-major h layout makes
// every sc1 access a full 256B-per-wave coalesced transaction.
// ---------------------------------------------------------------------------
__device__ __forceinline__ void store_coh_u32(uint32_t* p, uint32_t v) {
  (void)__hip_atomic_exchange(p, v, __ATOMIC_RELAXED, __HIP_MEMORY_SCOPE_AGENT);
}
__device__ __forceinline__ uint32_t load_coh_u32(const uint32_t* p) {
  return __hip_atomic_load(p, __ATOMIC_RELAXED, __HIP_MEMORY_SCOPE_AGENT);
}

// gsum addressing: 2-way-max bank pattern via XOR of bit4 with (row>>2)&1
#define GIDX(row, col) (((row) << 6) + ((col) ^ ((((row) >> 2) & 1) << 4)))

// ---------------------------------------------------------------------------
// Persistent LSTM, MFMA + LDS A-frags + LDS-staged B (R18).
// grid = 64 WGs x 512 threads; WG g owns units [g*8, g*8+8) = 32 gate rows,
// ALL 64 batches. Wave wu = ONE C-tile: rt = wu>>2, bt = wu&3.
// Per step:
//  1. stage full h (16384 words) hb->HL: 32 coalesced sc1 loads/thread,
//     conflict-free LDS writes (row = 8i+wu, col = lane).
//  2. MFMA over K=512: A via ds_read_b128 from WA (R17, 0 conflicts);
//     B gathered from HL[kpair][66] (pad 66: bank=(8lq+2m+l15)%32, 2-way max
//     = free per m136).
//  3. gsum (+pre-gates), elementwise 2 cells/thread (tid<256), h-store
//     COALESCED (thread(p,eb) -> hb[(g*4+p)*64+eb], 256B/wave-quarter).
//  4. vmcnt(0) release + 64-arrival monotonic barrier (proven).
// LDS (dynamic, 108544 B): WA 32KB | HL 256x66 u32 | gsum 32x64 f32.
// ---------------------------------------------------------------------------
__global__ __launch_bounds__(512) void lstm_persistent(
    const float* __restrict__ mem,   // [B][1280]
    const float* __restrict__ Whh,   // [4H][H] f32
    float* __restrict__ PG,          // [T][4H][B]
    uint32_t* __restrict__ hb,       // [2][256][64] packed bf16x2, unit-major
    float* __restrict__ outmem,      // [B][1280]
    unsigned* __restrict__ bar)      // cnt@0, gen@64
{
  extern __shared__ uint32_t smem[];
  uint32_t* WA = smem;               // [2048 slots][4] u32 = 32 KB
  uint32_t* HL = smem + 8192;        // [256][66] u32 = 67584 B
  float*  gsum = (float*)(smem + 8192 + 16896);  // [32*64] f32 = 8 KB

  const int g    = blockIdx.x;       // 0..63
  const int tid  = threadIdx.x;
  const int wu   = tid >> 6;         // wave 0..7
  const int lane = tid & 63;
  const int l15  = lane & 15;
  const int lq   = lane >> 4;        // 0..3
  const int bt   = wu & 3;           // batch tile 0..3
  const int rt   = wu >> 2;          // row tile 0..1
  const int u0   = g * 8;

  unsigned* cnt = bar;
  unsigned* gen = bar + 64;

  // ---- stage W slice into LDS in A-fragment order (once; R17-proven) ----
  #pragma unroll
  for (int s = 0; s < 4; ++s) {
    int slot = s * 512 + tid;          // 0..2047
    int srt  = slot >> 10;             // 0..1
    int rem  = slot & 1023;
    int sks  = rem >> 6;               // 0..15
    int ln   = rem & 63;
    int sl15 = ln & 15, slq = ln >> 4;
    int lr   = srt * 16 + sl15;        // local gate row
    int grow = (lr >> 3) * HS + u0 + (lr & 7);
    const float* wp = Whh + (size_t)grow * HS + slq * 8 + sks * 32;
    float4 x0 = *(const float4*)(wp);
    float4 x1 = *(const float4*)(wp + 4);
    uint32_t* dst = WA + (size_t)slot * 4;
    dst[0] = bf16r(x0.x) | (bf16r(x0.y) << 16);
    dst[1] = bf16r(x0.z) | (bf16r(x0.w) << 16);
    dst[2] = bf16r(x1.x) | (bf16r(x1.y) << 16);
    dst[3] = bf16r(x1.z) | (bf16r(x1.w) << 16);
  }

  // ---- elementwise state: tid<256, thread = (pair p = tid>>6, batch eb) ----
  const int p = tid >> 6;            // unit-pair 0..3 (valid for tid<256)
  const int eb = lane;
  float c0 = 0.f, c1 = 0.f, m0 = 0.f, m1 = 0.f, h0l = 0.f, h1l = 0.f;
  if (tid < 256) {
    c0 = mem[(size_t)eb * 1280 + 768 + u0 + 2 * p];
    c1 = mem[(size_t)eb * 1280 + 768 + u0 + 2 * p + 1];
    if (u0 < HHALF) {
      m0 = mem[(size_t)eb * 1280 + u0 + 2 * p];
      m1 = mem[(size_t)eb * 1280 + u0 + 2 * p + 1];
    }
  }

  // ---- pg prefetch for t=0 (1 tile x 4 regs per lane) ----
  float pg[4];
  #pragma unroll
  for (int r = 0; r < 4; ++r) {
    int lr = rt * 16 + lq * 4 + r;
    pg[r] = PG[((size_t)0 * R4H + (lr >> 3) * HS + u0 + (lr & 7)) * BB + bt * 16 + l15];
  }

  __syncthreads();  // W staged

  const uint32_t* waBase = WA + ((size_t)(rt * 16) * 64 + lane) * 4;
  const int hlCol = bt * 16 + l15;

  for (int t = 0; t < TT; ++t) {
    // ---- 1. stage h: coalesced sc1 loads -> conflict-free LDS writes ----
    {
      const uint32_t* hcur = hb + (size_t)(t & 1) * HB_STRIDE;
      uint32_t hv[32];
      #pragma unroll
      for (int i = 0; i < 32; ++i) hv[i] = load_coh_u32(hcur + tid + i * 512);
      #pragma unroll
      for (int i = 0; i < 32; ++i) {
        int w = tid + i * 512;                  // kpair = 8i+wu, b = lane
        HL[(w >> 6) * 66 + (w & 63)] = hv[i];
      }
    }
    __syncthreads();

    // ---- 2. MFMA over K=512: A from WA (b128), B gathered from HL ----
    f32x4 acc = {0.f, 0.f, 0.f, 0.f};
    #pragma unroll
    for (int ks = 0; ks < 16; ++ks) {
      short8v av = *(const short8v*)(waBase + ks * 256);  // ds_read_b128
      union { uint32_t u[4]; short8v v; } bf;
      #pragma unroll
      for (int m = 0; m < 4; ++m)
        bf.u[m] = HL[(ks * 16 + lq * 4 + m) * 66 + hlCol];
      acc = __builtin_amdgcn_mfma_f32_16x16x32_bf16(av, bf.v, acc, 0, 0, 0);
    }

    // ---- add pre-gates, write to gsum (2-way-max banks) ----
    {
      const int colw = bt * 16 + l15;
      #pragma unroll
      for (int r = 0; r < 4; ++r) {
        int row = rt * 16 + lq * 4 + r;
        gsum[GIDX(row, colw)] = acc[r] + pg[r];
      }
    }
    __syncthreads();

    // ---- 3. elementwise: 2 cells (units u0+2p, u0+2p+1) x batch eb ----
    if (tid < 256) {
      const int ul0 = 2 * p, ul1 = 2 * p + 1;
      float gi0 = gsum[GIDX( 0 + ul0, eb)];
      float gf0 = gsum[GIDX( 8 + ul0, eb)];
      float gg0 = gsum[GIDX(16 + ul0, eb)];
      float go0 = gsum[GIDX(24 + ul0, eb)];
      float gi1 = gsum[GIDX( 0 + ul1, eb)];
      float gf1 = gsum[GIDX( 8 + ul1, eb)];
      float gg1 = gsum[GIDX(16 + ul1, eb)];
      float go1 = gsum[GIDX(24 + ul1, eb)];
      float si0 = 1.f / (1.f + __expf(-gi0));
      float sf0 = 1.f / (1.f + __expf(-gf0));
      float so0 = 1.f / (1.f + __expf(-go0));
      float si1 = 1.f / (1.f + __expf(-gi1));
      float sf1 = 1.f / (1.f + __expf(-gf1));
      float so1 = 1.f / (1.f + __expf(-go1));
      c0 = sf0 * c0 + si0 * tanhf(gg0);
      c1 = sf1 * c1 + si1 * tanhf(gg1);
      float h0 = so0 * tanhf(c0);
      float h1 = so1 * tanhf(c1);
      h0l = h0; h1l = h1;
      // COALESCED unit-major store: hb[(g*4+p)*64 + eb], lanes contiguous
      store_coh_u32(&hb[(size_t)((t + 1) & 1) * HB_STRIDE + (size_t)(g * 4 + p) * 64 + eb],
                    bf16r(h0) | (bf16r(h1) << 16));
      float out0 = h0, out1 = h1;
      if (u0 < HHALF) { m0 = fmaxf(m0, h0); m1 = fmaxf(m1, h1); out0 = m0; out1 = m1; }
      PG[((size_t)t * R4H + u0 + 2 * p) * BB + eb]     = out0;  // stash
      PG[((size_t)t * R4H + u0 + 2 * p + 1) * BB + eb] = out1;
    }

    // ---- 4. barrier: release = vmcnt(0) on the exchange h-stores ----
    asm volatile("s_waitcnt vmcnt(0)" ::: "memory");
    __syncthreads();
    // pg prefetch for t+1 hides under the barrier
    if (t + 1 < TT) {
      #pragma unroll
      for (int r = 0; r < 4; ++r) {
        int lr = rt * 16 + lq * 4 + r;
        pg[r] = PG[((size_t)(t + 1) * R4H + (lr >> 3) * HS + u0 + (lr & 7)) * BB + bt * 16 + l15];
      }
    }
    if (tid == 0) {
      unsigned a = __hip_atomic_fetch_add(cnt, 1u, __ATOMIC_RELAXED,
                                          __HIP_MEMORY_SCOPE_AGENT);
      if (a == 64u * (unsigned)(t + 1) - 1u)
        (void)__hip_atomic_exchange(gen, (unsigned)(t + 1), __ATOMIC_RELAXED,
                                    __HIP_MEMORY_SCOPE_AGENT);
      // failsafe cap: fast wrong-answer instead of a hang; expected wait ~us.
      int spins = 0;
      while (__hip_atomic_load(gen, __ATOMIC_RELAXED,
                               __HIP_MEMORY_SCOPE_AGENT) < (unsigned)(t + 1)) {
        __builtin_amdgcn_s_sleep(1);
        if (++spins > (1 << 16)) break;
      }
    }
    __syncthreads();
  }

  // ---- finals ----
  if (tid < 256) {
    outmem[(size_t)eb * 1280 + 256 + u0 + 2 * p]     = h0l;
    outmem[(size_t)eb * 1280 + 256 + u0 + 2 * p + 1] = h1l;
    outmem[(size_t)eb * 1280 + 768 + u0 + 2 * p]     = c0;
    outmem[(size_t)eb * 1280 + 768 + u0 + 2 * p + 1] = c1;
    if (u0 < HHALF) {
      outmem[(size_t)eb * 1280 + u0 + 2 * p]     = m0;
      outmem[(size_t)eb * 1280 + u0 + 2 * p + 1] = m1;
    }
  }
}

// ---------------------------------------------------------------------------
// Phase 3: out[b][t][u] = PG[t][u][b]  (u < 512)
// ---------------------------------------------------------------------------
__global__ __launch_bounds__(256) void transpose_out(
    const float* __restrict__ PG, float* __restrict__ out)
{
  __shared__ __align__(16) float tileS[64][68];
  const int t = blockIdx.x;
  const int u0 = blockIdx.y * 64;
  const int tid = threadIdx.x;

  {
    int cg = tid & 15, rg = tid >> 4;
    const float* src = PG + (size_t)t * R4H * BB + (size_t)u0 * BB;
    #pragma unroll
    for (int i = 0; i < 4; ++i) {
      int u = rg * 4 + i;
      float4 v = *(const float4*)(src + (size_t)u * BB + cg * 4);
      *(float4*)&tileS[u][cg * 4] = v;
    }
  }
  __syncthreads();
  {
    int ug = tid & 15, bg = tid >> 4;
    #pragma unroll
    for (int i = 0; i < 4; ++i) {
      int b = bg * 4 + i;
      float4 o;
      o.x = tileS[ug * 4 + 0][b];
      o.y = tileS[ug * 4 + 1][b];
      o.z = tileS[ug * 4 + 2][b];
      o.w = tileS[ug * 4 + 3][b];
      *(float4*)&out[((size_t)b * TT + t) * HS + u0 + ug * 4] = o;
    }
  }
}

// ---------------------------------------------------------------------------
extern "C" void kernel_launch(void* const* d_in, const int* in_sizes, int n_in,
                              void* d_out, int out_size, void* d_ws, size_t ws_size,
                              hipStream_t stream)
{
  const float* X   = (const float*)d_in[0];
  const float* mem = (const float*)d_in[1];
  const float* Wih = (const float*)d_in[2];
  const float* Whh = (const float*)d_in[3];
  const float* bih = (const float*)d_in[4];
  const float* bhh = (const float*)d_in[5];

  float* out = (float*)d_out;
  float* outmem = out + (size_t)BB * TT * HS;

  float* PG     = (float*)d_ws;                      // 512*2048*64 f32 = 256 MB
  uint32_t* hbp = (uint32_t*)(PG + (size_t)TT * R4H * BB);  // 2*16384 u32
  unsigned* bar = (unsigned*)(hbp + 2 * HB_STRIDE);  // 2048 u32

  const int dyn_lds = 108544;  // WA 32768 + HL 67584 + gsum 8192
  (void)hipFuncSetAttribute((const void*)lstm_persistent,
                            hipFuncAttributeMaxDynamicSharedMemorySize, dyn_lds);

  hipMemsetAsync(bar, 0, 2048 * sizeof(unsigned), stream);
  init_h<<<dim3(HB_STRIDE / 256), dim3(256), 0, stream>>>(mem, hbp);
  pregemm<<<dim3(TT, 32), dim3(256), 0, stream>>>(X, Wih, bih, bhh, PG);
  lstm_persistent<<<dim3(64), dim3(512), dyn_lds, stream>>>(mem, Whh, PG, hbp, outmem, bar);
  transpose_out<<<dim3(TT, 8), dim3(256), 0, stream>>>(PG, out);
}